// Round 4
// baseline (638.996 us; speedup 1.0000x reference)
//
#include <hip/hip_runtime.h>

// Residual VQ: B=32, D=64, L=4096, NCB=4, K=512.
// out: z_q_aggregated [B][NCB][D][L] f32, then indices [B][L][NCB] (as f32).
//
// Bit-exact reproduction of the reference float32 pipeline (validated absmax=0):
//   dot[t][k]: single-accumulator FMA chain, d ascending 0..63
//   sx, se:    numpy pairwise 8-accumulator sum of squares, exact bracketing
//   d2 = (sx - 2*dot) + se     (two f32 roundings; 2*dot exact)
//   argmin:    first minimum (lowest k)
//   cascade:   x_res -= e[idx]; z_q += e[idx] in plain f32
//
// v4: single-buffered ebuf (v3's double buffer cost 16.6 KB LDS and capped
// residency at ~2 blocks/CU -> 1.8 waves/SIMD -> VALUBusy 55%). 25.9 KB LDS
// + VGPR<=128 gives 4 blocks/CU (4 waves/SIMD). Extra barrier per s-stage is
// the price; async reg-prefetch of the next chunk is kept. Inner loop uses
// explicit float4-member FMAs (no local arrays -> no shuffle movs).

#define LL   4096
#define DD   64
#define KK   512
#define NCB  4
#define TB   32      // tokens per block
#define NTHR 256     // 4 waves; wave w owns tokens w*8..w*8+7
#define XS   36      // x_lds row stride (floats): 32 tokens + 4 pad (16B align)
#define ES   260     // ebuf row stride (floats): 256 k' + 4 pad
#define EBUFN (16 * ES)

#define ZQ_ELEMS (32LL * NCB * DD * LL)   // 33,554,432 floats

// numpy pairwise sum of squares, n=64, exact op order (8 accumulators)
__device__ __forceinline__ float np_pairwise_sq64(const float* p) {
#pragma clang fp contract(off)
    float r[8];
#pragma unroll
    for (int j = 0; j < 8; ++j) { float s = p[j] * p[j]; r[j] = s; }
#pragma unroll
    for (int i = 8; i < 64; i += 8)
#pragma unroll
        for (int j = 0; j < 8; ++j) { float s = p[i + j] * p[i + j]; r[j] = r[j] + s; }
    return ((r[0] + r[1]) + (r[2] + r[3])) + ((r[4] + r[5]) + (r[6] + r[7]));
}

// ---------------- Kernel A: se[c][k] = np.sum(e*e, -1) ----------------
__global__ void se_kernel(const float* __restrict__ cb, float* __restrict__ se) {
    int t = blockIdx.x * blockDim.x + threadIdx.x;
    if (t >= NCB * KK) return;
    se[t] = np_pairwise_sq64(cb + (size_t)t * DD);
}

// ---------------- Main kernel ----------------
__global__ __launch_bounds__(NTHR) void rvq_kernel(const float* __restrict__ x_in,
                                                   const float* __restrict__ cb,
                                                   const float* __restrict__ se,
                                                   float* __restrict__ out) {
    __shared__ float ebuf[EBUFN];       // single-buffered codebook chunk [dd][k']
    __shared__ float x_lds[DD * XS];    // residual [d][tok]

    const int tid  = threadIdx.x;
    const int lane = tid & 63;
    const int w8   = (tid >> 6) << 3;   // wave's first token

    const long T0 = (long)blockIdx.x * TB;
    const int b  = (int)(T0 >> 12);
    const int l0 = (int)(T0 & 4095);

    // ---- stage x tile: x_lds[d][tok] = x_in[b][d][l0+tok] ----
    {
        const float* xb = x_in + (size_t)b * DD * LL + l0;
        const int dd0 = tid >> 3;
        const int t4  = (tid & 7) << 2;
#pragma unroll
        for (int it = 0; it < 2; ++it) {
            const int d = it * 32 + dd0;
            const float4 v = *reinterpret_cast<const float4*>(xb + (size_t)d * LL + t4);
            *reinterpret_cast<float4*>(&x_lds[d * XS + t4]) = v;
        }
    }

    // staging thread mapping: thread -> (d-quad sq, k' base sk)
    const int sq = tid & 3;
    const int sk = tid >> 2;

    // prefetch stage (c=0, s=0)
    float4 sv0, sv1, sv2, sv3;
    {
        const float* ec = cb + (size_t)(sq << 2);
        sv0 = *reinterpret_cast<const float4*>(ec + (size_t)(sk +   0) * DD);
        sv1 = *reinterpret_cast<const float4*>(ec + (size_t)(sk +  64) * DD);
        sv2 = *reinterpret_cast<const float4*>(ec + (size_t)(sk + 128) * DD);
        sv3 = *reinterpret_cast<const float4*>(ec + (size_t)(sk + 192) * DD);
    }

    __syncthreads();   // x_lds visible

    float zq[8];       // z_q[d = i*8 + (lane>>3)][tok = w8 + (lane&7)]
#pragma unroll
    for (int t = 0; t < 8; ++t) zq[t] = 0.f;

    const int sxj = lane & 7;   // accumulator index j of pairwise sum
    const int sxt = lane >> 3;  // token (within wave) this lane-group handles
    const int myt = lane & 7;   // residual-update: own token within wave
    const int da  = lane >> 3;  // residual-update: dim sub-index

#pragma unroll 1
    for (int c = 0; c < NCB; ++c) {
        // ---- sx: lane-parallel numpy pairwise (exact bracketing via xor tree) ----
        float a3;
        {
            float r;
            {
#pragma clang fp contract(off)
                float p = x_lds[sxj * XS + w8 + sxt];
                r = p * p;
#pragma unroll
                for (int i = 1; i < 8; ++i) {
                    float q = x_lds[(i * 8 + sxj) * XS + w8 + sxt];
                    r = r + q * q;
                }
            }
            // ((r0+r1)+(r2+r3)) + ((r4+r5)+(r6+r7)) for token sxt at lanes j=0
            float o1 = __shfl_xor(r, 1, 64);
            float a1 = r + o1;
            float o2 = __shfl_xor(a1, 2, 64);
            float a2 = a1 + o2;
            float o4 = __shfl_xor(a2, 4, 64);
            a3 = a2 + o4;
        }

        float b1v[8]; int b1i[8];
#pragma unroll
        for (int t = 0; t < 8; ++t) { b1v[t] = __builtin_inff(); b1i[t] = 0; }

        float acc[8][4];   // [token][g], k = h*256 + lane*4 + g

#pragma unroll 1
        for (int s = 0; s < 8; ++s) {        // s = h*4 + m
            // ebuf free here: trailing barrier of s-1 (or end-of-c / x barrier)
            // transpose-write staged regs: ebuf[dd][k'] = cb[k'][m*16+dd]
            ebuf[(sq * 4 + 0) * ES + sk      ] = sv0.x;
            ebuf[(sq * 4 + 1) * ES + sk      ] = sv0.y;
            ebuf[(sq * 4 + 2) * ES + sk      ] = sv0.z;
            ebuf[(sq * 4 + 3) * ES + sk      ] = sv0.w;
            ebuf[(sq * 4 + 0) * ES + sk +  64] = sv1.x;
            ebuf[(sq * 4 + 1) * ES + sk +  64] = sv1.y;
            ebuf[(sq * 4 + 2) * ES + sk +  64] = sv1.z;
            ebuf[(sq * 4 + 3) * ES + sk +  64] = sv1.w;
            ebuf[(sq * 4 + 0) * ES + sk + 128] = sv2.x;
            ebuf[(sq * 4 + 1) * ES + sk + 128] = sv2.y;
            ebuf[(sq * 4 + 2) * ES + sk + 128] = sv2.z;
            ebuf[(sq * 4 + 3) * ES + sk + 128] = sv2.w;
            ebuf[(sq * 4 + 0) * ES + sk + 192] = sv3.x;
            ebuf[(sq * 4 + 1) * ES + sk + 192] = sv3.y;
            ebuf[(sq * 4 + 2) * ES + sk + 192] = sv3.z;
            ebuf[(sq * 4 + 3) * ES + sk + 192] = sv3.w;

            __syncthreads();   // staged chunk visible to all waves

            // async-stage split: issue next chunk's global loads now; their
            // L2 latency hides under the dd-loop below.
            {
                int nc = c, ns = s + 1;
                if (ns == 8) { nc = c + 1; ns = 0; }
                if (nc < NCB) {
                    const float* ec = cb + ((size_t)(nc * KK + (ns >> 2) * 256)) * DD
                                         + (size_t)((ns & 3) * 16 + (sq << 2));
                    sv0 = *reinterpret_cast<const float4*>(ec + (size_t)(sk +   0) * DD);
                    sv1 = *reinterpret_cast<const float4*>(ec + (size_t)(sk +  64) * DD);
                    sv2 = *reinterpret_cast<const float4*>(ec + (size_t)(sk + 128) * DD);
                    sv3 = *reinterpret_cast<const float4*>(ec + (size_t)(sk + 192) * DD);
                }
            }

            if ((s & 3) == 0) {
#pragma unroll
                for (int t = 0; t < 8; ++t)
#pragma unroll
                    for (int g = 0; g < 4; ++g) acc[t][g] = 0.f;
            }

            const int mbase = (s & 3) * 16;
#pragma unroll
            for (int dd = 0; dd < 16; ++dd) {
                const int d = mbase + dd;
                // lane's 4 contiguous k's: one ds_read_b128, conflict-free
                const float4 e4  = *reinterpret_cast<const float4*>(&ebuf[dd * ES + (lane << 2)]);
                // wave's 8 tokens at dim d: two broadcast float4 reads
                const float4 xa  = *reinterpret_cast<const float4*>(&x_lds[d * XS + w8]);
                const float4 xb4 = *reinterpret_cast<const float4*>(&x_lds[d * XS + w8 + 4]);
#define FMA4(T, XV)                                   \
                acc[T][0] = fmaf(XV, e4.x, acc[T][0]); \
                acc[T][1] = fmaf(XV, e4.y, acc[T][1]); \
                acc[T][2] = fmaf(XV, e4.z, acc[T][2]); \
                acc[T][3] = fmaf(XV, e4.w, acc[T][3]);
                FMA4(0, xa.x)  FMA4(1, xa.y)  FMA4(2, xa.z)  FMA4(3, xa.w)
                FMA4(4, xb4.x) FMA4(5, xb4.y) FMA4(6, xb4.z) FMA4(7, xb4.w)
#undef FMA4
            }

            if ((s & 3) == 3) {   // fold this k-half: d2 = (sx - 2*dot) + se
#pragma clang fp contract(off)
                const int kb = (s >> 2) * 256 + (lane << 2);
                const float4 se4 = *reinterpret_cast<const float4*>(&se[c * KK + kb]);
                const float sev[4] = {se4.x, se4.y, se4.z, se4.w};
#pragma unroll
                for (int t = 0; t < 8; ++t) {
                    const float sxv = __shfl(a3, t << 3, 64);
#pragma unroll
                    for (int g = 0; g < 4; ++g) {
                        const float twod = 2.0f * acc[t][g];      // exact (x2)
                        const float d2 = (sxv - twod) + sev[g];
                        if (d2 < b1v[t]) { b1v[t] = d2; b1i[t] = kb + g; }
                    }
                }
            }

            __syncthreads();   // all reads of ebuf done before next overwrite
        }

        // cross-lane argmin (butterfly), tie -> lower index (first minimum)
#pragma unroll
        for (int t = 0; t < 8; ++t) {
            float v = b1v[t]; int i = b1i[t];
#pragma unroll
            for (int off = 32; off > 0; off >>= 1) {
                const float ov = __shfl_xor(v, off, 64);
                const int   oi = __shfl_xor(i, off, 64);
                if (ov < v || (ov == v && oi < i)) { v = ov; i = oi; }
            }
            b1i[t] = i;
        }

        // own token's code index (compile-time select; reg arrays can't be
        // runtime-indexed without going to scratch)
        int kown = 0;
#pragma unroll
        for (int t = 0; t < 8; ++t) if (myt == t) kown = b1i[t];

        // residual update + z_q accumulate, lane -> (tok=myt, d=i*8+da):
        // bank = 4*da + myt + w8 (mod 32) -> conflict-free; x_lds (tok,d) cells
        // are wave-private (tokens w8..w8+7), no cross-wave hazard.
        {
#pragma clang fp contract(off)
            const float* erow = cb + ((size_t)(c * KK) + kown) * DD + da;
#pragma unroll
            for (int i = 0; i < 8; ++i) {
                const float ev = erow[i * 8];
                const int xi = (i * 8 + da) * XS + w8 + myt;
                x_lds[xi] = x_lds[xi] - ev;
                zq[i] = zq[i] + ev;
            }
        }

        // indices (lane t of each wave stores its token)
#pragma unroll
        for (int t = 0; t < 8; ++t)
            if (lane == t)
                out[ZQ_ELEMS + ((size_t)b * LL + l0 + w8 + t) * NCB + c] = (float)b1i[t];

        // ---- z_q slice store via ebuf alias (free since s=7 trailing bar) ----
#pragma unroll
        for (int i = 0; i < 8; ++i)
            ebuf[(i * 8 + da) * XS + w8 + myt] = zq[i];
        __syncthreads();   // zq tile visible
        {
            float* zo = out + (((size_t)b * NCB + c) * DD) * LL + l0;
            const int c4 = (tid & 7) << 2;
            const int d0 = tid >> 3;
#pragma unroll
            for (int p = 0; p < 2; ++p) {
                const int d = p * 32 + d0;
                const float4 v = *reinterpret_cast<const float4*>(&ebuf[d * XS + c4]);
                *reinterpret_cast<float4*>(zo + (size_t)d * LL + c4) = v;
            }
        }
        __syncthreads();   // zq reads done before next c's s=0 overwrites ebuf
    }
}

extern "C" void kernel_launch(void* const* d_in, const int* in_sizes, int n_in,
                              void* d_out, int out_size, void* d_ws, size_t ws_size,
                              hipStream_t stream) {
    const float* x_in = (const float*)d_in[0];
    const float* cb   = (const float*)d_in[1];
    float* out = (float*)d_out;
    float* se  = (float*)d_ws;   // NCB*KK floats = 8 KB scratch

    se_kernel<<<dim3((NCB * KK + 255) / 256), dim3(256), 0, stream>>>(cb, se);
    rvq_kernel<<<dim3((32 * LL) / TB), dim3(NTHR), 0, stream>>>(x_in, cb, se, out);
}